// Round 3
// baseline (230.948 us; speedup 1.0000x reference)
//
#include <hip/hip_runtime.h>
#include <hip/hip_cooperative_groups.h>

namespace cg = cooperative_groups;

#define BB 32
#define TT 1024
#define DD 512
#define HH 10
#define WPAD 12            // padded W1a row in LDS (48B stride, 16B-aligned pieces)
#define CHUNK 64
#define NCH (TT / CHUNK)   // 16 chunks per batch row

// ws layout (floats): pc [BB*NCH*DD] at 0, sc [BB*NCH] after.

// ---------------------------------------------------------------------------
// Fully fused attention. Block = (b, 64-row chunk), 256 threads = 4 waves.
//   pre : stage W1a->LDS padded; compute cbh[b] redundantly per block;
//         tc==0 blocks copy rnn -> out second half.
//   A   : energies. wave wv covers f in [128wv,128wv+128), lane = row.
//         weights via wave-uniform LDS broadcast. partial-h -> LDS transpose.
//         energies bounded by ||W2||_1+|b2| (tanh in [-1,1]) => exp safe
//         without max subtraction -> single-pass softmax numerator.
//   B   : partial context for own chunk (data L2-hot from phase A).
//   COOP: grid sync, then tc==0 blocks combine partials -> context.
// ---------------------------------------------------------------------------
template <bool COOP>
__global__ __launch_bounds__(256, 2) void attn_k(
    const float* __restrict__ x, const float* __restrict__ rnn,
    const float* __restrict__ W1, const float* __restrict__ b1,
    const float* __restrict__ W2, const float* __restrict__ b2,
    float* __restrict__ pc, float* __restrict__ sc, float* __restrict__ out) {
  const int b = blockIdx.x >> 4;
  const int tc = blockIdx.x & (NCH - 1);
  const int tid = threadIdx.x;
  const int lane = tid & 63;
  const int wv = tid >> 6;

  __shared__ float wlds[DD * WPAD];           // 24 KB padded W1a
  __shared__ float upool[4 * CHUNK * 13];     // 13.3 KB: red[256][10] then hp[4][64][13]
  __shared__ float cbh_s[HH];
  __shared__ float wgt[CHUNK];

  // ---- pre: rnn copy (one block set per b) -------------------------------
  const float r0 = rnn[b * DD + tid];
  const float r1 = rnn[b * DD + tid + 256];
  if (tc == 0) {
    out[BB * DD + b * DD + tid] = r0;
    out[BB * DD + b * DD + tid + 256] = r1;
  }

  // ---- pre: W1a -> LDS (coalesced global read) ---------------------------
#pragma unroll
  for (int i = 0; i < DD * HH / 256; ++i) {
    const int idx = i * 256 + tid;
    const int f = idx / HH;
    const int h = idx - f * HH;
    wlds[f * WPAD + h] = W1[idx];
  }

  // ---- pre: cbh[b][h] = rnn[b]·W1[D:,h] + b1[h] (redundant per block) ----
  {
    float s[HH];
#pragma unroll
    for (int h = 0; h < HH; ++h)
      s[h] = r0 * W1[(DD + tid) * HH + h] + r1 * W1[(DD + tid + 256) * HH + h];
    float* red = upool;  // [256][HH]
#pragma unroll
    for (int h = 0; h < HH; ++h) red[tid * HH + h] = s[h];
    __syncthreads();
    for (int off = 128; off > 0; off >>= 1) {
      if (tid < off) {
#pragma unroll
        for (int h = 0; h < HH; ++h)
          red[tid * HH + h] += red[(tid + off) * HH + h];
      }
      __syncthreads();
    }
    if (tid < HH) cbh_s[tid] = red[tid] + b1[tid];
    __syncthreads();  // cbh_s ready; upool free for reuse; wlds ready
  }

  // ---- Phase A: energies -------------------------------------------------
  float (*hp)[CHUNK][13] = (float (*)[CHUNK][13])upool;
  const int row = b * TT + tc * CHUNK + lane;
  const float* xr = x + (size_t)row * DD + wv * 128;
  const float* wp = wlds + wv * 128 * WPAD;

  float acc[HH];
#pragma unroll
  for (int h = 0; h < HH; ++h) acc[h] = 0.f;

#pragma unroll 4
  for (int k = 0; k < 32; ++k) {
    const float4 xv = *reinterpret_cast<const float4*>(xr + k * 4);
    const float xa[4] = {xv.x, xv.y, xv.z, xv.w};
#pragma unroll
    for (int j = 0; j < 4; ++j) {
      const float4 wa =
          *reinterpret_cast<const float4*>(wp + (k * 4 + j) * WPAD);
      const float4 wb =
          *reinterpret_cast<const float4*>(wp + (k * 4 + j) * WPAD + 4);
      const float2 wc =
          *reinterpret_cast<const float2*>(wp + (k * 4 + j) * WPAD + 8);
      const float xs = xa[j];
      acc[0] = fmaf(xs, wa.x, acc[0]);
      acc[1] = fmaf(xs, wa.y, acc[1]);
      acc[2] = fmaf(xs, wa.z, acc[2]);
      acc[3] = fmaf(xs, wa.w, acc[3]);
      acc[4] = fmaf(xs, wb.x, acc[4]);
      acc[5] = fmaf(xs, wb.y, acc[5]);
      acc[6] = fmaf(xs, wb.z, acc[6]);
      acc[7] = fmaf(xs, wb.w, acc[7]);
      acc[8] = fmaf(xs, wc.x, acc[8]);
      acc[9] = fmaf(xs, wc.y, acc[9]);
    }
  }

#pragma unroll
  for (int h = 0; h < HH; ++h) hp[wv][lane][h] = acc[h];
  __syncthreads();

  if (tid < 64) {
    float e = b2[0];
#pragma unroll
    for (int h = 0; h < HH; ++h) {
      const float v = hp[0][lane][h] + hp[1][lane][h] + hp[2][lane][h] +
                      hp[3][lane][h] + cbh_s[h];
      const float z = __expf(2.f * v);
      const float th = 1.f - 2.f / (z + 1.f);  // tanh(v)
      e = fmaf(th, W2[h], e);
    }
    float w = __expf(fmaxf(e, 0.f));  // bounded energy: no max subtraction
    wgt[lane] = w;
#pragma unroll
    for (int off = 32; off > 0; off >>= 1) w += __shfl_xor(w, off, 64);
    if (lane == 0) sc[b * NCH + tc] = w;
  }
  __syncthreads();

  // ---- Phase B: partial context (chunk is L2-hot) ------------------------
  const int d0 = tid * 2;
  const float* xb = x + (size_t)(b * TT + tc * CHUNK) * DD + d0;
  float ax = 0.f, ay = 0.f;
#pragma unroll 8
  for (int r = 0; r < CHUNK; ++r) {
    const float wr = wgt[r];
    const float2 xv = *reinterpret_cast<const float2*>(xb + (size_t)r * DD);
    ax = fmaf(wr, xv.x, ax);
    ay = fmaf(wr, xv.y, ay);
  }
  *reinterpret_cast<float2*>(pc + (size_t)(b * NCH + tc) * DD + d0) =
      make_float2(ax, ay);

  // ---- combine (cooperative path only) -----------------------------------
  if constexpr (COOP) {
    __threadfence();
    cg::this_grid().sync();
    if (tc == 0) {
      float ssum = 0.f;
#pragma unroll
      for (int c = 0; c < NCH; ++c) ssum += sc[b * NCH + c];
      float cx = 0.f, cy = 0.f;
#pragma unroll
      for (int c = 0; c < NCH; ++c) {
        const float2 v = *reinterpret_cast<const float2*>(
            pc + (size_t)(b * NCH + c) * DD + d0);
        cx += v.x;
        cy += v.y;
      }
      const float inv = 1.f / ssum;
      *reinterpret_cast<float2*>(out + b * DD + d0) =
          make_float2(cx * inv, cy * inv);
    }
  }
}

// Fallback combine kernel (non-cooperative path).
__global__ __launch_bounds__(256) void k2_combine(
    const float* __restrict__ pc, const float* __restrict__ sc,
    float* __restrict__ out) {
  const int b = blockIdx.x;
  const int d0 = threadIdx.x * 2;
  float ssum = 0.f;
#pragma unroll
  for (int c = 0; c < NCH; ++c) ssum += sc[b * NCH + c];
  float ax = 0.f, ay = 0.f;
#pragma unroll
  for (int c = 0; c < NCH; ++c) {
    const float2 v =
        *reinterpret_cast<const float2*>(pc + (size_t)(b * NCH + c) * DD + d0);
    ax += v.x;
    ay += v.y;
  }
  const float inv = 1.f / ssum;
  *reinterpret_cast<float2*>(out + b * DD + d0) =
      make_float2(ax * inv, ay * inv);
}

// ---------------------------------------------------------------------------
extern "C" void kernel_launch(void* const* d_in, const int* in_sizes, int n_in,
                              void* d_out, int out_size, void* d_ws,
                              size_t ws_size, hipStream_t stream) {
  const float* cbhg = (const float*)d_in[0];  // [B, T, D]
  const float* rnn = (const float*)d_in[1];   // [B, D]
  const float* W1 = (const float*)d_in[2];    // [2D, H]
  const float* b1 = (const float*)d_in[3];    // [H]
  const float* W2 = (const float*)d_in[4];    // [H, 1]
  const float* b2 = (const float*)d_in[5];    // [1]
  float* out = (float*)d_out;                 // context [B,D] then rnn [B,D]

  float* pc = (float*)d_ws;                   // [BB*NCH*DD]
  float* sc = pc + BB * NCH * DD;             // [BB*NCH]

  void* args[] = {(void*)&cbhg, (void*)&rnn, (void*)&W1, (void*)&b1,
                  (void*)&W2,   (void*)&b2,  (void*)&pc, (void*)&sc,
                  (void*)&out};
  hipError_t err = hipLaunchCooperativeKernel(
      (const void*)attn_k<true>, dim3(BB * NCH), dim3(256), args, 0, stream);
  if (err != hipSuccess) {
    // Fallback: same fused kernel without grid sync + tiny combine.
    attn_k<false><<<BB * NCH, 256, 0, stream>>>(cbhg, rnn, W1, b1, W2, b2, pc,
                                                sc, out);
    k2_combine<<<BB, 256, 0, stream>>>(pc, sc, out);
  }
}

// Round 4
// 226.099 us; speedup vs baseline: 1.0214x; 1.0214x over previous
//
#include <hip/hip_runtime.h>
#include <hip/hip_cooperative_groups.h>

namespace cg = cooperative_groups;

#define BB 32
#define TT 1024
#define DD 512
#define HH 10
#define CHUNK 64
#define NCH (TT / CHUNK)   // 16 chunks per batch row

// ws layout (floats): pc [BB*NCH*DD] at 0, sc [BB*NCH] after.

// ---------------------------------------------------------------------------
// Fully fused attention, single HBM pass over x.
// Block = (b, 64-row chunk), 256 threads = 4 waves, wave = 16 rows.
// Per row: wave-coalesced loads (lane L holds f = 4L..4L+3 and 256+4L..+3,
// each load instr = 1KB contiguous), W1a kept in 80 VGPRs/lane,
// 6-step butterfly finishes the 10 dots, bounded-energy softmax
// (e <= ||W2||_1+|b2|, tanh in [-1,1] => exp safe, no max pass),
// then ctx += w * x on the registers already holding x (no re-read).
// ---------------------------------------------------------------------------
template <bool COOP>
__global__ __launch_bounds__(256, 2) void attn_k(
    const float* __restrict__ x, const float* __restrict__ rnn,
    const float* __restrict__ W1, const float* __restrict__ b1,
    const float* __restrict__ W2, const float* __restrict__ b2,
    float* __restrict__ pc, float* __restrict__ sc, float* __restrict__ out) {
  const int b = blockIdx.x >> 4;
  const int tc = blockIdx.x & (NCH - 1);
  const int tid = threadIdx.x;
  const int lane = tid & 63;
  const int wv = tid >> 6;
  const int f0 = lane * 4;

  __shared__ float ctx4[4][DD];      // per-wave partial context (8 KB)
  __shared__ float wpart[4][HH + 2]; // cbh wave partials
  __shared__ float cbh_s[HH];
  __shared__ float ws4[4];

  // ---- rnn copy (one block set per b) ------------------------------------
  const float r0 = rnn[b * DD + tid];
  const float r1 = rnn[b * DD + tid + 256];
  if (tc == 0) {
    out[BB * DD + b * DD + tid] = r0;
    out[BB * DD + b * DD + tid + 256] = r1;
  }

  // ---- cbh[h] = rnn[b]·W1[D:,h] + b1[h] (redundant per block, cheap) -----
  {
    float s[HH];
    const float* wb0 = W1 + (size_t)(DD + tid) * HH;
    const float* wb1 = W1 + (size_t)(DD + tid + 256) * HH;
#pragma unroll
    for (int h = 0; h < HH; ++h) s[h] = r0 * wb0[h] + r1 * wb1[h];
#pragma unroll
    for (int h = 0; h < HH; ++h) {
#pragma unroll
      for (int off = 32; off; off >>= 1) s[h] += __shfl_xor(s[h], off, 64);
    }
    // static register indexing only (runtime-indexed reg arrays -> scratch)
#pragma unroll
    for (int h = 0; h < HH; ++h)
      if (lane == h) wpart[wv][h] = s[h];
    __syncthreads();
    if (tid < HH)
      cbh_s[tid] =
          wpart[0][tid] + wpart[1][tid] + wpart[2][tid] + wpart[3][tid] + b1[tid];
    __syncthreads();
  }

  // ---- per-lane weight fragments: W1a rows f0..f0+3 and 256+f0.. ---------
  float wA[4][HH], wB[4][HH];
#pragma unroll
  for (int k = 0; k < 4; ++k) {
#pragma unroll
    for (int h = 0; h < HH; ++h) {
      wA[k][h] = W1[(size_t)(f0 + k) * HH + h];
      wB[k][h] = W1[(size_t)(256 + f0 + k) * HH + h];
    }
  }
  float w2r[HH], creg[HH];
#pragma unroll
  for (int h = 0; h < HH; ++h) w2r[h] = W2[h];
#pragma unroll
  for (int h = 0; h < HH; ++h) creg[h] = cbh_s[h];
  const float b2v = b2[0];

  // ---- main loop: 16 rows per wave, software-pipelined loads -------------
  const float* xrow = x + (size_t)(b * TT + tc * CHUNK + wv * 16) * DD;
  float cx0 = 0.f, cx1 = 0.f, cx2 = 0.f, cx3 = 0.f;
  float cy0 = 0.f, cy1 = 0.f, cy2 = 0.f, cy3 = 0.f;
  float wsum = 0.f;

  float4 xa = *reinterpret_cast<const float4*>(xrow + f0);
  float4 xb = *reinterpret_cast<const float4*>(xrow + 256 + f0);

#pragma unroll 4
  for (int i = 0; i < 16; ++i) {
    float4 na, nb;
    if (i < 15) {
      na = *reinterpret_cast<const float4*>(xrow + (size_t)(i + 1) * DD + f0);
      nb = *reinterpret_cast<const float4*>(xrow + (size_t)(i + 1) * DD + 256 + f0);
    }
    float acc[HH];
#pragma unroll
    for (int h = 0; h < HH; ++h) {
      float v = xa.x * wA[0][h];
      v = fmaf(xa.y, wA[1][h], v);
      v = fmaf(xa.z, wA[2][h], v);
      v = fmaf(xa.w, wA[3][h], v);
      v = fmaf(xb.x, wB[0][h], v);
      v = fmaf(xb.y, wB[1][h], v);
      v = fmaf(xb.z, wB[2][h], v);
      v = fmaf(xb.w, wB[3][h], v);
      acc[h] = v;
    }
#pragma unroll
    for (int h = 0; h < HH; ++h) {
#pragma unroll
      for (int off = 32; off; off >>= 1) acc[h] += __shfl_xor(acc[h], off, 64);
    }
    // epilogue (redundant across lanes; all lanes hold full sums)
    float e = b2v;
#pragma unroll
    for (int h = 0; h < HH; ++h) {
      const float v = acc[h] + creg[h];
      const float z = __expf(2.f * v);
      const float th = 1.f - 2.f / (z + 1.f);  // tanh(v)
      e = fmaf(th, w2r[h], e);
    }
    const float w = __expf(fmaxf(e, 0.f));  // bounded energy: no max-sub
    wsum += w;
    cx0 = fmaf(w, xa.x, cx0);
    cx1 = fmaf(w, xa.y, cx1);
    cx2 = fmaf(w, xa.z, cx2);
    cx3 = fmaf(w, xa.w, cx3);
    cy0 = fmaf(w, xb.x, cy0);
    cy1 = fmaf(w, xb.y, cy1);
    cy2 = fmaf(w, xb.z, cy2);
    cy3 = fmaf(w, xb.w, cy3);
    xa = na;
    xb = nb;
  }

  // ---- combine 4 wave-partials through LDS -------------------------------
  *reinterpret_cast<float4*>(&ctx4[wv][f0]) = make_float4(cx0, cx1, cx2, cx3);
  *reinterpret_cast<float4*>(&ctx4[wv][256 + f0]) =
      make_float4(cy0, cy1, cy2, cy3);
  if (lane == 0) ws4[wv] = wsum;
  __syncthreads();

  {
    const int d0 = tid, d1 = tid + 256;
    float* pcd = pc + (size_t)(b * NCH + tc) * DD;
    pcd[d0] = ctx4[0][d0] + ctx4[1][d0] + ctx4[2][d0] + ctx4[3][d0];
    pcd[d1] = ctx4[0][d1] + ctx4[1][d1] + ctx4[2][d1] + ctx4[3][d1];
    if (tid == 0) sc[b * NCH + tc] = ws4[0] + ws4[1] + ws4[2] + ws4[3];
  }

  // ---- cooperative combine ------------------------------------------------
  if constexpr (COOP) {
    __threadfence();
    cg::this_grid().sync();
    if (tc == 0) {
      const int d0 = tid * 2;
      float ssum = 0.f;
#pragma unroll
      for (int c = 0; c < NCH; ++c) ssum += sc[b * NCH + c];
      float ax = 0.f, ay = 0.f;
#pragma unroll
      for (int c = 0; c < NCH; ++c) {
        const float2 v = *reinterpret_cast<const float2*>(
            pc + (size_t)(b * NCH + c) * DD + d0);
        ax += v.x;
        ay += v.y;
      }
      const float inv = 1.f / ssum;
      *reinterpret_cast<float2*>(out + b * DD + d0) =
          make_float2(ax * inv, ay * inv);
    }
  }
}

// Fallback combine kernel (non-cooperative path).
__global__ __launch_bounds__(256) void k2_combine(
    const float* __restrict__ pc, const float* __restrict__ sc,
    float* __restrict__ out) {
  const int b = blockIdx.x;
  const int d0 = threadIdx.x * 2;
  float ssum = 0.f;
#pragma unroll
  for (int c = 0; c < NCH; ++c) ssum += sc[b * NCH + c];
  float ax = 0.f, ay = 0.f;
#pragma unroll
  for (int c = 0; c < NCH; ++c) {
    const float2 v =
        *reinterpret_cast<const float2*>(pc + (size_t)(b * NCH + c) * DD + d0);
    ax += v.x;
    ay += v.y;
  }
  const float inv = 1.f / ssum;
  *reinterpret_cast<float2*>(out + b * DD + d0) =
      make_float2(ax * inv, ay * inv);
}

// ---------------------------------------------------------------------------
extern "C" void kernel_launch(void* const* d_in, const int* in_sizes, int n_in,
                              void* d_out, int out_size, void* d_ws,
                              size_t ws_size, hipStream_t stream) {
  const float* cbhg = (const float*)d_in[0];  // [B, T, D]
  const float* rnn = (const float*)d_in[1];   // [B, D]
  const float* W1 = (const float*)d_in[2];    // [2D, H]
  const float* b1 = (const float*)d_in[3];    // [H]
  const float* W2 = (const float*)d_in[4];    // [H, 1]
  const float* b2 = (const float*)d_in[5];    // [1]
  float* out = (float*)d_out;                 // context [B,D] then rnn [B,D]

  float* pc = (float*)d_ws;                   // [BB*NCH*DD]
  float* sc = pc + BB * NCH * DD;             // [BB*NCH]

  void* args[] = {(void*)&cbhg, (void*)&rnn, (void*)&W1, (void*)&b1,
                  (void*)&W2,   (void*)&b2,  (void*)&pc, (void*)&sc,
                  (void*)&out};
  hipError_t err = hipLaunchCooperativeKernel(
      (const void*)attn_k<true>, dim3(BB * NCH), dim3(256), args, 0, stream);
  if (err != hipSuccess) {
    attn_k<false><<<BB * NCH, 256, 0, stream>>>(cbhg, rnn, W1, b1, W2, b2, pc,
                                                sc, out);
    k2_combine<<<BB, 256, 0, stream>>>(pc, sc, out);
  }
}

// Round 5
// 117.960 us; speedup vs baseline: 1.9578x; 1.9167x over previous
//
#include <hip/hip_runtime.h>

#define BB 32
#define TT 1024
#define DD 512
#define HH 10
#define CHUNK 64
#define NCH (TT / CHUNK)   // 16 chunks per batch row

// ws layout (floats): pc [BB*NCH*DD] at 0, sc [BB*NCH] after.

// ---------------------------------------------------------------------------
// Fused attention main kernel (regular launch — cooperative grid.sync was
// measured at ~100us of device-fence overhead in rounds 3/4; never again).
// Block = (b, 64-row chunk), 256 threads = 4 waves, wave = 16 rows.
// Per row: coalesced loads (lane L holds f = 4L..4L+3 and 256+4L..4L+3,
// each load instr = 1KB contiguous per wave), W1a kept in 80 VGPRs/lane,
// 6-step butterfly finishes the 10 dots, bounded-energy softmax
// (e <= ||W2||_1+|b2| since tanh in [-1,1] => exp safe, no max pass),
// context accumulated in-register on the x values already loaded
// (single HBM pass, no re-read, no atomics).
// ---------------------------------------------------------------------------
__global__ __launch_bounds__(256, 2) void attn_main(
    const float* __restrict__ x, const float* __restrict__ rnn,
    const float* __restrict__ W1, const float* __restrict__ b1,
    const float* __restrict__ W2, const float* __restrict__ b2,
    float* __restrict__ pc, float* __restrict__ sc, float* __restrict__ out) {
  const int b = blockIdx.x >> 4;
  const int tc = blockIdx.x & (NCH - 1);
  const int tid = threadIdx.x;
  const int lane = tid & 63;
  const int wv = tid >> 6;
  const int f0 = lane * 4;

  __shared__ float ctx4[4][DD];      // per-wave partial context (8 KB)
  __shared__ float wpart[4][HH + 2]; // cbh wave partials
  __shared__ float cbh_s[HH];
  __shared__ float ws4[4];

  // ---- rnn copy (one block set per b) ------------------------------------
  const float r0 = rnn[b * DD + tid];
  const float r1 = rnn[b * DD + tid + 256];
  if (tc == 0) {
    out[BB * DD + b * DD + tid] = r0;
    out[BB * DD + b * DD + tid + 256] = r1;
  }

  // ---- cbh[h] = rnn[b]·W1[D:,h] + b1[h] (redundant per block, cheap) -----
  {
    float s[HH];
    const float* wb0 = W1 + (size_t)(DD + tid) * HH;
    const float* wb1 = W1 + (size_t)(DD + tid + 256) * HH;
#pragma unroll
    for (int h = 0; h < HH; ++h) s[h] = r0 * wb0[h] + r1 * wb1[h];
#pragma unroll
    for (int h = 0; h < HH; ++h) {
#pragma unroll
      for (int off = 32; off; off >>= 1) s[h] += __shfl_xor(s[h], off, 64);
    }
    // static register indexing only (runtime-indexed reg arrays -> scratch)
#pragma unroll
    for (int h = 0; h < HH; ++h)
      if (lane == h) wpart[wv][h] = s[h];
    __syncthreads();
    if (tid < HH)
      cbh_s[tid] =
          wpart[0][tid] + wpart[1][tid] + wpart[2][tid] + wpart[3][tid] + b1[tid];
    __syncthreads();
  }

  // ---- per-lane weight fragments: W1a rows f0..f0+3 and 256+f0.. ---------
  float wA[4][HH], wB[4][HH];
#pragma unroll
  for (int k = 0; k < 4; ++k) {
#pragma unroll
    for (int h = 0; h < HH; ++h) {
      wA[k][h] = W1[(size_t)(f0 + k) * HH + h];
      wB[k][h] = W1[(size_t)(256 + f0 + k) * HH + h];
    }
  }
  float w2r[HH], creg[HH];
#pragma unroll
  for (int h = 0; h < HH; ++h) w2r[h] = W2[h];
#pragma unroll
  for (int h = 0; h < HH; ++h) creg[h] = cbh_s[h];
  const float b2v = b2[0];

  // ---- main loop: 16 rows per wave, software-pipelined loads -------------
  const float* xrow = x + (size_t)(b * TT + tc * CHUNK + wv * 16) * DD;
  float cx0 = 0.f, cx1 = 0.f, cx2 = 0.f, cx3 = 0.f;
  float cy0 = 0.f, cy1 = 0.f, cy2 = 0.f, cy3 = 0.f;
  float wsum = 0.f;

  float4 xa = *reinterpret_cast<const float4*>(xrow + f0);
  float4 xb = *reinterpret_cast<const float4*>(xrow + 256 + f0);

#pragma unroll 4
  for (int i = 0; i < 16; ++i) {
    float4 na, nb;
    if (i < 15) {
      na = *reinterpret_cast<const float4*>(xrow + (size_t)(i + 1) * DD + f0);
      nb = *reinterpret_cast<const float4*>(xrow + (size_t)(i + 1) * DD + 256 + f0);
    }
    float acc[HH];
#pragma unroll
    for (int h = 0; h < HH; ++h) {
      float v = xa.x * wA[0][h];
      v = fmaf(xa.y, wA[1][h], v);
      v = fmaf(xa.z, wA[2][h], v);
      v = fmaf(xa.w, wA[3][h], v);
      v = fmaf(xb.x, wB[0][h], v);
      v = fmaf(xb.y, wB[1][h], v);
      v = fmaf(xb.z, wB[2][h], v);
      v = fmaf(xb.w, wB[3][h], v);
      acc[h] = v;
    }
#pragma unroll
    for (int h = 0; h < HH; ++h) {
#pragma unroll
      for (int off = 32; off; off >>= 1) acc[h] += __shfl_xor(acc[h], off, 64);
    }
    // epilogue (redundant across lanes; all lanes hold full sums)
    float e = b2v;
#pragma unroll
    for (int h = 0; h < HH; ++h) {
      const float v = acc[h] + creg[h];
      const float z = __expf(2.f * v);
      const float th = 1.f - 2.f * __builtin_amdgcn_rcpf(z + 1.f);  // tanh(v)
      e = fmaf(th, w2r[h], e);
    }
    const float w = __expf(fmaxf(e, 0.f));  // bounded energy: no max-sub
    wsum += w;
    cx0 = fmaf(w, xa.x, cx0);
    cx1 = fmaf(w, xa.y, cx1);
    cx2 = fmaf(w, xa.z, cx2);
    cx3 = fmaf(w, xa.w, cx3);
    cy0 = fmaf(w, xb.x, cy0);
    cy1 = fmaf(w, xb.y, cy1);
    cy2 = fmaf(w, xb.z, cy2);
    cy3 = fmaf(w, xb.w, cy3);
    xa = na;
    xb = nb;
  }

  // ---- combine 4 wave-partials through LDS -------------------------------
  *reinterpret_cast<float4*>(&ctx4[wv][f0]) = make_float4(cx0, cx1, cx2, cx3);
  *reinterpret_cast<float4*>(&ctx4[wv][256 + f0]) =
      make_float4(cy0, cy1, cy2, cy3);
  if (lane == 0) ws4[wv] = wsum;
  __syncthreads();

  {
    const int d0 = tid, d1 = tid + 256;
    float* pcd = pc + (size_t)(b * NCH + tc) * DD;
    pcd[d0] = ctx4[0][d0] + ctx4[1][d0] + ctx4[2][d0] + ctx4[3][d0];
    pcd[d1] = ctx4[0][d1] + ctx4[1][d1] + ctx4[2][d1] + ctx4[3][d1];
    if (tid == 0) sc[b * NCH + tc] = ws4[0] + ws4[1] + ws4[2] + ws4[3];
  }
}

// ---------------------------------------------------------------------------
// Combine partials: context[b][d] = sum_c pc[b][c][d] / sum_c sc[b][c]
// ---------------------------------------------------------------------------
__global__ __launch_bounds__(256) void k2_combine(
    const float* __restrict__ pc, const float* __restrict__ sc,
    float* __restrict__ out) {
  const int b = blockIdx.x;
  const int d0 = threadIdx.x * 2;
  float ssum = 0.f;
#pragma unroll
  for (int c = 0; c < NCH; ++c) ssum += sc[b * NCH + c];
  float ax = 0.f, ay = 0.f;
#pragma unroll
  for (int c = 0; c < NCH; ++c) {
    const float2 v =
        *reinterpret_cast<const float2*>(pc + (size_t)(b * NCH + c) * DD + d0);
    ax += v.x;
    ay += v.y;
  }
  const float inv = 1.f / ssum;
  *reinterpret_cast<float2*>(out + b * DD + d0) =
      make_float2(ax * inv, ay * inv);
}

// ---------------------------------------------------------------------------
extern "C" void kernel_launch(void* const* d_in, const int* in_sizes, int n_in,
                              void* d_out, int out_size, void* d_ws,
                              size_t ws_size, hipStream_t stream) {
  const float* cbhg = (const float*)d_in[0];  // [B, T, D]
  const float* rnn = (const float*)d_in[1];   // [B, D]
  const float* W1 = (const float*)d_in[2];    // [2D, H]
  const float* b1 = (const float*)d_in[3];    // [H]
  const float* W2 = (const float*)d_in[4];    // [H, 1]
  const float* b2 = (const float*)d_in[5];    // [1]
  float* out = (float*)d_out;                 // context [B,D] then rnn [B,D]

  float* pc = (float*)d_ws;                   // [BB*NCH*DD]
  float* sc = pc + BB * NCH * DD;             // [BB*NCH]

  attn_main<<<BB * NCH, 256, 0, stream>>>(cbhg, rnn, W1, b1, W2, b2, pc, sc,
                                          out);
  k2_combine<<<BB, 256, 0, stream>>>(pc, sc, out);
}